// Round 11
// baseline (95.990 us; speedup 1.0000x reference)
//
#include <hip/hip_runtime.h>

// SpanNERDecoder: B=4, S=512, D=768, L=10, E=25, C=9, N=5075 spans.
// scores[b,n,c] = max_{p in [st,en)} we[b,p,:] . W[:D,c] + (len_embed[len] . W[D:,c] + b[c])
//
// ROUND 11: depth-3 prefetch kernel in DOUBLE-LAUNCH form.
// Round-5 measured the depth-1 kernel double-launched: 91.72us (kernel ~12.2us,
// floor ~67.4us). Same launch structure here => improvement = (91.72 - dur)/2,
// independent of the floor estimate.
// Theory: we[] is L2-cold every replay (d_in restored); depth-1 made a 10-deep
// ~900cy dependent HBM chain. 3 rows in flight cuts it ~3x. VGPR stays in the
// 2-waves/SIMD band (occupancy unchanged -> isolates prefetch depth; round-7
// showed occupancy itself is not the constraint).

#define SS 512
#define DD 768
#define LL 10
#define EE 25
#define CC 9
#define NSPANS 5075

__device__ __forceinline__ float wave_sum64(float v) {
    int x;
    // quad_perm [1,0,3,2] == xor1
    x = __builtin_amdgcn_update_dpp(0, __float_as_int(v), 0xB1, 0xF, 0xF, true);
    v += __int_as_float(x);
    // quad_perm [2,3,0,1] == xor2
    x = __builtin_amdgcn_update_dpp(0, __float_as_int(v), 0x4E, 0xF, 0xF, true);
    v += __int_as_float(x);
    // row_half_mirror == xor4 (values already quad-uniform)
    x = __builtin_amdgcn_update_dpp(0, __float_as_int(v), 0x141, 0xF, 0xF, true);
    v += __int_as_float(x);
    // row_mirror == xor8 (values already 8-uniform)
    x = __builtin_amdgcn_update_dpp(0, __float_as_int(v), 0x140, 0xF, 0xF, true);
    v += __int_as_float(x);
    v += __shfl_xor(v, 16, 64);
    v += __shfl_xor(v, 32, 64);
    return v;
}

__global__ __launch_bounds__(256, 2) void spanner_kernel(
    const float* __restrict__ we,    // [B,S,D]
    const float* __restrict__ lene,  // [L,E]
    const float* __restrict__ W,     // [D+E, C]
    const float* __restrict__ bias,  // [C]
    float* __restrict__ out)         // [B,N,C]
{
    __shared__ float lenW[LL][CC];
    const int t = threadIdx.x;

    const int lane = t & 63;
    const int gid  = blockIdx.x * 4 + (t >> 6);   // 0..2047 == B*S
    const int b    = gid >> 9;
    const int i    = gid & (SS - 1);
    const int cnt  = min(LL, SS - i);
    const int base = (i <= SS - LL) ? i * LL
                     : (NSPANS - ((SS - i) * (SS - i + 1)) / 2);

    const float4* rowbase = reinterpret_cast<const float4*>(we) + (size_t)(b * SS) * (DD / 4);

    // --- Issue 3 rows (9 independent float4 loads) FIRST: these are the
    // L2-cold critical chain. Slots rotate statically below.
    float4 R[3][3];
    {
        const int i1 = min(i + 1, SS - 1), i2 = min(i + 2, SS - 1);
        const float4* p0 = rowbase + (size_t)i  * (DD / 4);
        const float4* p1 = rowbase + (size_t)i1 * (DD / 4);
        const float4* p2 = rowbase + (size_t)i2 * (DD / 4);
        R[0][0] = p0[lane]; R[0][1] = p0[64 + lane]; R[0][2] = p0[128 + lane];
        R[1][0] = p1[lane]; R[1][1] = p1[64 + lane]; R[1][2] = p1[128 + lane];
        R[2][0] = p2[lane]; R[2][1] = p2[64 + lane]; R[2][2] = p2[128 + lane];
    }

    // --- Issue W-fragment loads next (27 float4), unpack after the sync.
    float4 wv4[3][9];
#pragma unroll
    for (int c0 = 0; c0 < 3; ++c0) {
        const float4* wp = reinterpret_cast<const float4*>(W + (c0 * 256 + lane * 4) * CC);
#pragma unroll
        for (int j = 0; j < 9; ++j) wv4[c0][j] = wp[j];
    }

    // --- lenW table (threads 0..89); its loads/FMA overlap the row latency.
    if (t < LL * CC) {
        const int l = t / CC, c = t % CC;
        float s = bias[c];
#pragma unroll
        for (int e = 0; e < EE; ++e)
            s += lene[l * EE + e] * W[(DD + e) * CC + c];
        lenW[l][c] = s;
    }
    __syncthreads();

    float Wr[3][4][CC];
#pragma unroll
    for (int c0 = 0; c0 < 3; ++c0) {
        const float* wf = reinterpret_cast<const float*>(&wv4[c0][0]);
#pragma unroll
        for (int q = 0; q < 4; ++q)
#pragma unroll
            for (int c = 0; c < CC; ++c)
                Wr[c0][q][c] = wf[q * CC + c];
    }

    float m[3][4];
#pragma unroll
    for (int c0 = 0; c0 < 3; ++c0)
#pragma unroll
        for (int q = 0; q < 4; ++q) m[c0][q] = -INFINITY;

    float acc[5][CC];
    float res[LL];

#pragma unroll
    for (int k = 0; k < LL; ++k) {
        // Fold row slot (k%3) into running max, then refill it with row k+3.
        {
            const float* f;
            f = (const float*)&R[k % 3][0];
#pragma unroll
            for (int q = 0; q < 4; ++q) m[0][q] = fmaxf(m[0][q], f[q]);
            f = (const float*)&R[k % 3][1];
#pragma unroll
            for (int q = 0; q < 4; ++q) m[1][q] = fmaxf(m[1][q], f[q]);
            f = (const float*)&R[k % 3][2];
#pragma unroll
            for (int q = 0; q < 4; ++q) m[2][q] = fmaxf(m[2][q], f[q]);
        }
        if (k + 3 < LL) {
            const int nr = min(i + k + 3, SS - 1);
            const float4* rp = rowbase + (size_t)nr * (DD / 4);
            R[k % 3][0] = rp[lane];
            R[k % 3][1] = rp[64 + lane];
            R[k % 3][2] = rp[128 + lane];
        }

        // Per-lane partial dot: 12 dims x 9 classes.
        const int kk = k % 5;
#pragma unroll
        for (int c = 0; c < CC; ++c) acc[kk][c] = 0.0f;
#pragma unroll
        for (int c0 = 0; c0 < 3; ++c0)
#pragma unroll
            for (int q = 0; q < 4; ++q)
#pragma unroll
                for (int c = 0; c < CC; ++c)
                    acc[kk][c] = fmaf(m[c0][q], Wr[c0][q][c], acc[kk][c]);

        // Batched reduction every 5 spans: 45 independent chains.
        if (kk == 4) {
#pragma unroll
            for (int kb = 0; kb < 5; ++kb) {
                float s[CC];
#pragma unroll
                for (int c = 0; c < CC; ++c) s[c] = wave_sum64(acc[kb][c]);
                float v = s[0];
#pragma unroll
                for (int c = 1; c < CC; ++c) v = (lane == c) ? s[c] : v;
                res[k - 4 + kb] = v;
            }
        }
    }

    float* const outb = out + ((size_t)b * NSPANS + base) * CC;
    if (lane < CC) {
#pragma unroll
        for (int k = 0; k < LL; ++k)
            if (k < cnt) outb[k * CC + lane] = res[k] + lenW[k][lane];
    }
}

extern "C" void kernel_launch(void* const* d_in, const int* in_sizes, int n_in,
                              void* d_out, int out_size, void* d_ws, size_t ws_size,
                              hipStream_t stream) {
    const float* we   = (const float*)d_in[0];
    const float* lene = (const float*)d_in[1];
    const float* W    = (const float*)d_in[2];
    const float* bias = (const float*)d_in[3];
    float* out        = (float*)d_out;

    // DIAGNOSTIC double-launch (same structure as round 5's measurement):
    // improvement_per_launch = (91.72 - dur_us) / 2, floor-independent.
    spanner_kernel<<<512, 256, 0, stream>>>(we, lene, W, bias, out);
    spanner_kernel<<<512, 256, 0, stream>>>(we, lene, W, bias, out);
}

// Round 12
// 77.360 us; speedup vs baseline: 1.2408x; 1.2408x over previous
//
#include <hip/hip_runtime.h>

// SpanNERDecoder: B=4, S=512, D=768, L=10, E=25, C=9, N=5075 spans.
// scores[b,n,c] = max_{p in [st,en)} we[b,p,:] . W[:D,c] + (len_embed[len] . W[D:,c] + b[c])
//
// ROUND 12: round-4 kernel (best measured: 79.56us single-launch) + XCD-aware
// block swizzle ONLY.
// Diagnosis history: occupancy-null (r7), prefetch-depth negative (r11).
// New theory: linear blockIdx round-robins consecutive gids across the 8
// non-coherent per-XCD L2s; gid i and i+1 share 9/10 rows, so every XCD
// re-fetches ~all of we[] from HBM (~50MB instead of ~7MB). Swizzle
// work=(bid%8)*64+bid/8 gives each XCD a contiguous 256-gid range -> row
// reuse becomes L2-local.

#define SS 512
#define DD 768
#define LL 10
#define EE 25
#define CC 9
#define NSPANS 5075

__device__ __forceinline__ float wave_sum64(float v) {
    int x;
    // quad_perm [1,0,3,2] == xor1
    x = __builtin_amdgcn_update_dpp(0, __float_as_int(v), 0xB1, 0xF, 0xF, true);
    v += __int_as_float(x);
    // quad_perm [2,3,0,1] == xor2
    x = __builtin_amdgcn_update_dpp(0, __float_as_int(v), 0x4E, 0xF, 0xF, true);
    v += __int_as_float(x);
    // row_half_mirror == xor4 (values already quad-uniform)
    x = __builtin_amdgcn_update_dpp(0, __float_as_int(v), 0x141, 0xF, 0xF, true);
    v += __int_as_float(x);
    // row_mirror == xor8 (values already 8-uniform)
    x = __builtin_amdgcn_update_dpp(0, __float_as_int(v), 0x140, 0xF, 0xF, true);
    v += __int_as_float(x);
    v += __shfl_xor(v, 16, 64);
    v += __shfl_xor(v, 32, 64);
    return v;
}

__global__ __launch_bounds__(256, 2) void spanner_kernel(
    const float* __restrict__ we,    // [B,S,D]
    const float* __restrict__ lene,  // [L,E]
    const float* __restrict__ W,     // [D+E, C]
    const float* __restrict__ bias,  // [C]
    float* __restrict__ out)         // [B,N,C]
{
    __shared__ float lenW[LL][CC];
    const int t = threadIdx.x;

    // XCD-aware swizzle: dispatch slot -> work chunk. Slots n with n%8==k go
    // to XCD k (round-robin dispatch) and get contiguous chunks [k*64,(k+1)*64).
    const int wb   = (blockIdx.x & 7) * 64 + (blockIdx.x >> 3);

    const int lane = t & 63;
    const int gid  = wb * 4 + (t >> 6);           // 0..2047 == B*S
    const int b    = gid >> 9;
    const int i    = gid & (SS - 1);
    const int cnt  = min(LL, SS - i);
    const int base = (i <= SS - LL) ? i * LL
                     : (NSPANS - ((SS - i) * (SS - i + 1)) / 2);

    // Fold len_embed @ W[D:,:] + bias into a 10x9 table (once per block).
    if (t < LL * CC) {
        const int l = t / CC, c = t % CC;
        float s = bias[c];
#pragma unroll
        for (int e = 0; e < EE; ++e)
            s += lene[l * EE + e] * W[(DD + e) * CC + c];
        lenW[l][c] = s;
    }
    __syncthreads();

    // W fragment: lane owns dims d = c0*256 + lane*4 + q. 36 contiguous floats
    // per c0 -> 9 float4 loads each.
    float Wr[3][4][CC];
#pragma unroll
    for (int c0 = 0; c0 < 3; ++c0) {
        const float4* wp = reinterpret_cast<const float4*>(W + (c0 * 256 + lane * 4) * CC);
        float4 wv[9];
#pragma unroll
        for (int j = 0; j < 9; ++j) wv[j] = wp[j];
        const float* wf = reinterpret_cast<const float*>(wv);
#pragma unroll
        for (int q = 0; q < 4; ++q)
#pragma unroll
            for (int c = 0; c < CC; ++c)
                Wr[c0][q][c] = wf[q * CC + c];
    }

    const float4* rowbase = reinterpret_cast<const float4*>(we) + (size_t)(b * SS) * (DD / 4);

    float4 r0 = rowbase[(size_t)i * (DD / 4) + lane];
    float4 r1 = rowbase[(size_t)i * (DD / 4) + 64 + lane];
    float4 r2 = rowbase[(size_t)i * (DD / 4) + 128 + lane];

    float m[3][4];
#pragma unroll
    for (int c0 = 0; c0 < 3; ++c0)
#pragma unroll
        for (int q = 0; q < 4; ++q) m[c0][q] = -INFINITY;

    float acc[5][CC];
    float res[LL];

#pragma unroll
    for (int k = 0; k < LL; ++k) {
        // Fold current row into the running max.
        {
            const float* f;
            f = (const float*)&r0;
#pragma unroll
            for (int q = 0; q < 4; ++q) m[0][q] = fmaxf(m[0][q], f[q]);
            f = (const float*)&r1;
#pragma unroll
            for (int q = 0; q < 4; ++q) m[1][q] = fmaxf(m[1][q], f[q]);
            f = (const float*)&r2;
#pragma unroll
            for (int q = 0; q < 4; ++q) m[2][q] = fmaxf(m[2][q], f[q]);
        }

        // Prefetch next row (clamped; spans past cnt are never stored).
        if (k + 1 < LL) {
            const int nr = min(i + k + 1, SS - 1);
            r0 = rowbase[(size_t)nr * (DD / 4) + lane];
            r1 = rowbase[(size_t)nr * (DD / 4) + 64 + lane];
            r2 = rowbase[(size_t)nr * (DD / 4) + 128 + lane];
        }

        // Per-lane partial dot: 12 dims x 9 classes.
        const int kk = k % 5;
#pragma unroll
        for (int c = 0; c < CC; ++c) acc[kk][c] = 0.0f;
#pragma unroll
        for (int c0 = 0; c0 < 3; ++c0)
#pragma unroll
            for (int q = 0; q < 4; ++q)
#pragma unroll
                for (int c = 0; c < CC; ++c)
                    acc[kk][c] = fmaf(m[c0][q], Wr[c0][q][c], acc[kk][c]);

        // Batched reduction every 5 spans: 45 independent chains.
        if (kk == 4) {
#pragma unroll
            for (int kb = 0; kb < 5; ++kb) {
                float s[CC];
#pragma unroll
                for (int c = 0; c < CC; ++c) s[c] = wave_sum64(acc[kb][c]);
                float v = s[0];
#pragma unroll
                for (int c = 1; c < CC; ++c) v = (lane == c) ? s[c] : v;
                res[k - 4 + kb] = v;
            }
        }
    }

    float* const outb = out + ((size_t)b * NSPANS + base) * CC;
    if (lane < CC) {
#pragma unroll
        for (int k = 0; k < LL; ++k)
            if (k < cnt) outb[k * CC + lane] = res[k] + lenW[k][lane];
    }
}

extern "C" void kernel_launch(void* const* d_in, const int* in_sizes, int n_in,
                              void* d_out, int out_size, void* d_ws, size_t ws_size,
                              hipStream_t stream) {
    const float* we   = (const float*)d_in[0];
    const float* lene = (const float*)d_in[1];
    const float* W    = (const float*)d_in[2];
    const float* bias = (const float*)d_in[3];
    float* out        = (float*)d_out;

    // 2048 waves = B*S; 4 waves per 256-thread block -> 512 blocks.
    spanner_kernel<<<512, 256, 0, stream>>>(we, lene, W, bias, out);
}